// Round 19
// baseline (186.898 us; speedup 1.0000x reference)
//
#include <hip/hip_runtime.h>
#include <hip/hip_bf16.h>

typedef __attribute__((ext_vector_type(8))) short bf16x8;
typedef __attribute__((ext_vector_type(4))) float f32x4;

#define B_   4
#define T_   2048
#define DIM_ 1024
#define H_   64
#define NS_  32
#define K_   8
#define HV_  32
#define NTOK  (B_ * T_)   /* 8192 */
#define RA_N  128         /* router logits(64) | a(64) */
#define CL_   64          /* scan chunk length */
#define NC_   (T_ / CL_)  /* 32 chunks per slot */
#define NSLOT (B_ * K_)   /* 32 */
#define NPAIR (NTOK * K_) /* 65536 */

// ---------------------------------------------------------------- helpers
__device__ __forceinline__ void gld_lds16(const void* g, void* s) {
  __builtin_amdgcn_global_load_lds(
      (const __attribute__((address_space(1))) void*)g,
      (__attribute__((address_space(3))) void*)s, 16, 0, 0);
}
__device__ __forceinline__ float silu_f(float x) { return x / (1.f + expf(-x)); }

// ---------------------------------------------------------------- prep
__global__ __launch_bounds__(256) void cast_bf16(const float* __restrict__ in,
                                                 __hip_bfloat16* __restrict__ out, int n4) {
  int i = blockIdx.x * 256 + threadIdx.x;
  if (i >= n4) return;
  const float4 v = *(const float4*)(in + (size_t)i * 4);
  union { short4 s4; __hip_bfloat16 h[4]; } u;
  u.h[0] = __float2bfloat16(v.x); u.h[1] = __float2bfloat16(v.y);
  u.h[2] = __float2bfloat16(v.z); u.h[3] = __float2bfloat16(v.w);
  *(short4*)(out + (size_t)i * 4) = u.s4;
}

// Wg[h][r][d], r<32: Wq[h*32+r], r<64: Wk[h*32+r-32], else Wv[h*32+r-64]  (bf16)
__global__ __launch_bounds__(256) void build_wg(const float* __restrict__ Wq,
                                                const float* __restrict__ Wk,
                                                const float* __restrict__ Wv,
                                                __hip_bfloat16* __restrict__ Wg) {
  int i = blockIdx.x * 256 + threadIdx.x;           // 6144*1024/4
  int row = i >> 8, c4 = (i & 255) * 4;
  int h = row / 96, r = row - h * 96;
  const float* src = (r < 32) ? (Wq + ((size_t)h * 32 + r) * 1024)
                   : (r < 64) ? (Wk + ((size_t)h * 32 + r - 32) * 1024)
                              : (Wv + ((size_t)h * 32 + r - 64) * 1024);
  const float4 v = *(const float4*)(src + c4);
  union { short4 s4; __hip_bfloat16 hh[4]; } u;
  u.hh[0] = __float2bfloat16(v.x); u.hh[1] = __float2bfloat16(v.y);
  u.hh[2] = __float2bfloat16(v.z); u.hh[3] = __float2bfloat16(v.w);
  *(short4*)(Wg + (size_t)row * 1024 + c4) = u.s4;
}

// B2[d][s*32+v] = Wo[d][v]  (slot-replicated Wo, bf16), 1024x256
__global__ __launch_bounds__(256) void build_b2(const float* __restrict__ Wo,
                                                __hip_bfloat16* __restrict__ B2) {
  int i = blockIdx.x * 256 + threadIdx.x;
  int d = i >> 8, c = i & 255;
  B2[i] = __float2bfloat16(Wo[d * 32 + (c & 31)]);
}

// WTp[(d>>2)*512 + h*4 + (d&3)] = (h<64 ? Wr : Wa)[h][d]  fp32 packed.
__global__ __launch_bounds__(256) void build_wt(const float* __restrict__ Wr,
                                                const float* __restrict__ Wa,
                                                float* __restrict__ WTp) {
  int i = blockIdx.x * 256 + threadIdx.x;           // 131072
  int d = i >> 7, h = i & 127;
  const float v = (h < 64) ? Wr[h * 1024 + d] : Wa[(h - 64) * 1024 + d];
  WTp[(d >> 2) * 512 + h * 4 + (d & 3)] = v;
}

// ---------------------------------------------------------------- router GEMM (fp32 exact)
// v5: R18's depth-1 exposed ~150cyc/step; fix = depth-3 (4-buffer rotation,
// vmcnt(6): 3 stages x 2 loads in flight -> 390cyc coverage > L2 latency).
// Per-wave private weight buffers -> NO barriers in the loop; only the
// x-tile prologue barriers. LDS 64KB -> 2 blk/CU, ILP-carried.
__global__ __launch_bounds__(256, 2) void router_gemm(const float* __restrict__ x,
                                                      const float* __restrict__ WTp,
                                                      float* __restrict__ RA) {
  __shared__ __align__(16) float Lx[8 * 1024];        // 32 KB
  __shared__ __align__(16) float Lw[4][4][512];       // 32 KB (per-wave 4-deep dbuf)
  const int w = threadIdx.x >> 6, l = threadIdx.x & 63;
  const int t0 = blockIdx.x * 8;
#pragma unroll
  for (int j = 0; j < 8; ++j) {
    const int seg = w * 8 + j;
    gld_lds16(x + (size_t)t0 * DIM_ + seg * 256 + l * 4, Lx + seg * 256);
  }
  const int cb = w * 64;                              // wave's first 4-dim chunk
  auto WSTAGE = [&](int b, int t) {                   // 2 loads: heads 0-63 | 64-127
    gld_lds16(WTp + (size_t)(cb + t) * 512 + l * 4,       &Lw[w][b][0]   + l * 4);
    gld_lds16(WTp + (size_t)(cb + t) * 512 + 256 + l * 4, &Lw[w][b][256] + l * 4);
  };
  WSTAGE(0, 0); WSTAGE(1, 1); WSTAGE(2, 2);
  asm volatile("s_waitcnt vmcnt(6)" ::: "memory");    // 8 x-loads retired (in-order)
  __builtin_amdgcn_s_barrier();

  const int dbase = w * 256;
  float a0[8] = {}, a1[8] = {};

  auto STEP = [&](int buf, int t) {
    const float4 w0 = *(const float4*)(&Lw[w][buf][l * 4]);
    const float4 w1 = *(const float4*)(&Lw[w][buf][256 + l * 4]);
    const int d = dbase + t * 4;
    float4 xv[8];
#pragma unroll
    for (int i = 0; i < 8; ++i) xv[i] = *(const float4*)(Lx + i * 1024 + d);
#pragma unroll
    for (int i = 0; i < 8; ++i) {
      a0[i] = fmaf(xv[i].x, w0.x, a0[i]);
      a0[i] = fmaf(xv[i].y, w0.y, a0[i]);
      a0[i] = fmaf(xv[i].z, w0.z, a0[i]);
      a0[i] = fmaf(xv[i].w, w0.w, a0[i]);
      a1[i] = fmaf(xv[i].x, w1.x, a1[i]);
      a1[i] = fmaf(xv[i].y, w1.y, a1[i]);
      a1[i] = fmaf(xv[i].z, w1.z, a1[i]);
      a1[i] = fmaf(xv[i].w, w1.w, a1[i]);
    }
  };

  for (int t = 0; t < 61; ++t) {
    WSTAGE((t + 3) & 3, t + 3);
    asm volatile("s_waitcnt vmcnt(6)" ::: "memory");  // buf t landed
    STEP(t & 3, t);
  }
  asm volatile("s_waitcnt vmcnt(4)" ::: "memory"); STEP(1, 61);
  asm volatile("s_waitcnt vmcnt(2)" ::: "memory"); STEP(2, 62);
  asm volatile("s_waitcnt vmcnt(0)" ::: "memory"); STEP(3, 63);

  __syncthreads();                       // all x reads done -> alias partials
  float* Lp = Lx;                        // [4][8][128] floats
#pragma unroll
  for (int i = 0; i < 8; ++i) {
    Lp[w * 1024 + i * 128 + l] = a0[i];
    Lp[w * 1024 + i * 128 + 64 + l] = a1[i];
  }
  __syncthreads();
  for (int o = threadIdx.x; o < 1024; o += 256) {
    const int ti = o >> 7, cc = o & 127;
    RA[(size_t)(t0 + ti) * RA_N + cc] =
        (Lp[0 * 1024 + ti * 128 + cc] + Lp[1 * 1024 + ti * 128 + cc]) +
        (Lp[2 * 1024 + ti * 128 + cc] + Lp[3 * 1024 + ti * 128 + cc]);
  }
}

// ---------------------------------------------------------------- top-k + decay (1 wave / token)
__global__ __launch_bounds__(256) void router_topk(const float* __restrict__ RA,
                                                   const float* __restrict__ A_log,
                                                   const float* __restrict__ dt_bias,
                                                   int* __restrict__ idxb,
                                                   float* __restrict__ rwb,
                                                   float* __restrict__ decb) {
  const int w = threadIdx.x >> 6, l = threadIdx.x & 63;
  const int m = blockIdx.x * 4 + w;
  float zcur = RA[(size_t)m * RA_N + l];
  const int idx = l;
  float z0 = 0.f, myz = 0.f;
  int myh = 0;
#pragma unroll
  for (int i = 0; i < 8; ++i) {
    float v = zcur; int vi = idx;
#pragma unroll
    for (int off = 1; off < 64; off <<= 1) {
      float ov = __shfl_xor(v, off);
      int   oi = __shfl_xor(vi, off);
      if (ov > v || (ov == v && oi < vi)) { v = ov; vi = oi; }
    }
    if (i == 0) z0 = v;
    if (l == i) { myz = v; myh = vi; }
    if (idx == vi) zcur = -__builtin_inff();
  }
  float e = (l < 8) ? expf(myz - z0) : 0.f;
  float es = e;
  es += __shfl_xor(es, 1); es += __shfl_xor(es, 2); es += __shfl_xor(es, 4);
  if (l < 8) {
    const float a  = RA[(size_t)m * RA_N + 64 + myh];
    const float xb = a + dt_bias[myh];
    const float dt = (xb > 20.f) ? xb : log1pf(expf(xb));
    idxb[m * 8 + l] = myh;
    rwb [m * 8 + l] = e / es;
    decb[m * 8 + l] = expf(-expf(A_log[myh]) * dt);
  }
}

// ---------------------------------------------------------------- head bucketing
__global__ void zero_cnt(int* __restrict__ cnt) {
  if (threadIdx.x < H_) cnt[threadIdx.x] = 0;
}

__global__ __launch_bounds__(256) void hist_bucket(const int* __restrict__ idxb,
                                                   int* __restrict__ cnt,
                                                   int* __restrict__ pairtok) {
  __shared__ int lh[H_];
  __shared__ int lcur[H_];
  const int tid = threadIdx.x;
  if (tid < H_) lh[tid] = 0;
  __syncthreads();
  const int base = blockIdx.x * (NPAIR / 32);   // 2048 pairs/block
  int hs[8];
#pragma unroll
  for (int j = 0; j < 8; ++j) {
    hs[j] = idxb[base + j * 256 + tid];
    atomicAdd(&lh[hs[j]], 1);
  }
  __syncthreads();
  if (tid < H_) lcur[tid] = atomicAdd(&cnt[tid], lh[tid]);
  __syncthreads();
#pragma unroll
  for (int j = 0; j < 8; ++j) {
    const int pos = atomicAdd(&lcur[hs[j]], 1);
    pairtok[hs[j] * NTOK + pos] = base + j * 256 + tid;
  }
}

// ---------------------------------------------------------------- grouped QKV projection
// R17 verified: 4 blk/CU, register prs via __shfl, 128B segments (1 cache
// line = transaction floor), counted vmcnt(5), both-sides XOR swizzle.
__global__ __launch_bounds__(256, 4) void grouped_qkv(const short* __restrict__ x_bf,
                                                      const short* __restrict__ Wg,
                                                      const int* __restrict__ pairtok,
                                                      const int* __restrict__ cnt,
                                                      const float* __restrict__ rwb,
                                                      const float* __restrict__ decb,
                                                      float* __restrict__ rec) {
  const int bid = blockIdx.x;
  const int h = bid & 63;                             // h%8 == bid%8 (XCD affinity)
  const int c = bid >> 6;                             // 0..127 chunk of 64 rows
  const int n = cnt[h];
  if (c * 64 >= n) return;
  __shared__ __align__(16) short stg[2][10240];       // 40,960 B exactly

  const int w = threadIdx.x >> 6, l = threadIdx.x & 63;
  const int lr = l & 15, lk = l >> 4;

  const int ri = c * 64 + w * 16 + l;
  int pid = -1;
  if (l < 16 && ri < n) pid = pairtok[h * NTOK + ri];
  const long fallback = (long)(pairtok[h * NTOK] >> 3);

  const int lrow8 = l >> 3, lslot = l & 7;
  const int swz = (lslot ^ lrow8) << 3;               // shorts within 64-short row
  const int p0 = __shfl(pid, lrow8);
  const int p1 = __shfl(pid, 8 + lrow8);
  const short* sa0 = x_bf + ((p0 >= 0) ? (long)(p0 >> 3) : fallback) * DIM_ + swz;
  const short* sa1 = x_bf + ((p1 >= 0) ? (long)(p1 >> 3) : fallback) * DIM_ + swz;
  const short* sb  = Wg + ((size_t)h * 96 + w * 24 + lrow8) * DIM_ + swz;

  auto STAGE = [&](int s, int t) {                    // 5 loads/wave
    const int k0 = t * 64;
    short* bb = stg[s];
    gld_lds16(sa0 + k0, bb + (w * 16) * 64);
    gld_lds16(sa1 + k0, bb + (w * 16 + 8) * 64);
#pragma unroll
    for (int j = 0; j < 3; ++j)
      gld_lds16(sb + (size_t)(j * 8) * DIM_ + k0, bb + 4096 + (w * 24 + j * 8) * 64);
  };

  f32x4 acc[6] = {};
  STAGE(0, 0);
  int cur = 0;
  for (int t = 0; t < 16; ++t) {
    if (t < 15) {
      STAGE(cur ^ 1, t + 1);
      asm volatile("s_waitcnt vmcnt(5) lgkmcnt(0)" ::: "memory");
    } else {
      asm volatile("s_waitcnt vmcnt(0) lgkmcnt(0)" ::: "memory");
    }
    __builtin_amdgcn_s_barrier();
    __builtin_amdgcn_sched_barrier(0);
    const short* bb = stg[cur];
#pragma unroll
    for (int kk = 0; kk < 2; ++kk) {
      const int sl = ((kk * 4 + lk) ^ (lr & 7)) << 3;
      const bf16x8 a = *(const bf16x8*)(bb + (w * 16 + lr) * 64 + sl);
#pragma unroll
      for (int j = 0; j < 6; ++j) {
        const bf16x8 bj = *(const bf16x8*)(bb + 4096 + (j * 16 + lr) * 64 + sl);
        acc[j] = __builtin_amdgcn_mfma_f32_16x16x32_bf16(a, bj, acc[j], 0, 0, 0);
      }
    }
    asm volatile("s_waitcnt lgkmcnt(0)" ::: "memory"); // reads retired before reuse
    __builtin_amdgcn_sched_barrier(0);
    __builtin_amdgcn_s_barrier();
    cur ^= 1;
  }

  // epilogue: row(within wave) = lk*4 + r; acc cols j0,j1=q j2,j3=k j4,j5=v
#pragma unroll
  for (int r = 0; r < 4; ++r) {
    const int p = __shfl(pid, lk * 4 + r);
    float q0v = silu_f(acc[0][r]), q1v = silu_f(acc[1][r]);
    float k0v = silu_f(acc[2][r]), k1v = silu_f(acc[3][r]);
    float v0 = silu_f(acc[4][r]), v1 = silu_f(acc[5][r]);
    float ssq = q0v * q0v + q1v * q1v;
    float ssk = k0v * k0v + k1v * k1v;
    ssq += __shfl_xor(ssq, 1); ssq += __shfl_xor(ssq, 2);
    ssq += __shfl_xor(ssq, 4); ssq += __shfl_xor(ssq, 8);
    ssk += __shfl_xor(ssk, 1); ssk += __shfl_xor(ssk, 2);
    ssk += __shfl_xor(ssk, 4); ssk += __shfl_xor(ssk, 8);
    const float rq = rsqrtf(ssq + 1e-6f), rk = rsqrtf(ssk + 1e-6f);
    if (p >= 0) {
      const int m = p >> 3, s = p & 7;
      const int b = m >> 11, t = m & (T_ - 1);
      float* rb = rec + (((size_t)(b * 8 + s)) * T_ + t) * 128;
      rb[lr]      = k0v * rk;
      rb[16 + lr] = k1v * rk;
      rb[32 + lr] = q0v * rq;
      rb[48 + lr] = q1v * rq;
      rb[64 + lr] = v0;
      rb[80 + lr] = v1;
      if (lr == 0) { rb[96] = decb[p]; rb[97] = rwb[p]; }
    }
  }
}

// ---------------------------------------------------------------- bf16 MFMA GEMM, C = A * B^T (final proj)
template <bool OUT_BF16>
__global__ __launch_bounds__(256) void gemm_bt(const short* __restrict__ A,
                                               const short* __restrict__ Bm,
                                               void* __restrict__ Cout,
                                               int M, int N, int K) {
  __shared__ __align__(16) short As[2][128 * 32];
  __shared__ __align__(16) short Bs[2][128 * 32];
  const int tid = threadIdx.x;
  const int w = tid >> 6, l = tid & 63;
  const int m0 = blockIdx.y * 128, n0 = blockIdx.x * 128;
  const int wr = (w >> 1) * 64, wc = (w & 1) * 64;
  const int rsub = l >> 2, csub = (l & 3) * 8;
  const int lr = l & 15, lk = l >> 4;
  f32x4 acc[4][4] = {};

  auto STAGE = [&](int buf, int k0) {
#pragma unroll
    for (int j = 0; j < 2; ++j) {
      const int ra = w * 32 + j * 16;
      gld_lds16(A  + (size_t)(m0 + ra + rsub) * K + k0 + csub, As[buf] + ra * 32);
      gld_lds16(Bm + (size_t)(n0 + ra + rsub) * K + k0 + csub, Bs[buf] + ra * 32);
    }
  };

  STAGE(0, 0);
  __syncthreads();
  int cur = 0;
  for (int k0 = 0; k0 < K; k0 += 32) {
    if (k0 + 32 < K) STAGE(cur ^ 1, k0 + 32);
    bf16x8 af[4], bfr[4];
#pragma unroll
    for (int i = 0; i < 4; ++i) af[i]  = *(const bf16x8*)(As[cur] + (wr + i * 16 + lr) * 32 + lk * 8);
#pragma unroll
    for (int j = 0; j < 4; ++j) bfr[j] = *(const bf16x8*)(Bs[cur] + (wc + j * 16 + lr) * 32 + lk * 8);
#pragma unroll
    for (int i = 0; i < 4; ++i)
#pragma unroll
      for (int j = 0; j < 4; ++j)
        acc[i][j] = __builtin_amdgcn_mfma_f32_16x16x32_bf16(af[i], bfr[j], acc[i][j], 0, 0, 0);
    __syncthreads();
    cur ^= 1;
  }
#pragma unroll
  for (int i = 0; i < 4; ++i)
#pragma unroll
    for (int j = 0; j < 4; ++j) {
      const size_t row0 = (size_t)m0 + wr + i * 16 + lk * 4;
      const size_t col  = (size_t)n0 + wc + j * 16 + lr;
#pragma unroll
      for (int r = 0; r < 4; ++r) {
        if constexpr (OUT_BF16)
          ((__hip_bfloat16*)Cout)[(row0 + r) * N + col] = __float2bfloat16(acc[i][j][r]);
        else
          ((float*)Cout)[(row0 + r) * N + col] = acc[i][j][r];
      }
    }
}

// ---------------------------------------------------------------- chunked scan: pass 1
__global__ __launch_bounds__(256) void scan_pass1(const float* __restrict__ rec,
                                                  float* __restrict__ ylocal,
                                                  float* __restrict__ Sloc,
                                                  float* __restrict__ Pc,
                                                  float* __restrict__ cumd) {
  __shared__ __align__(16) float R[CL_ * 128];   // 32 KB
  const int blk = blockIdx.x;
  const int bs = blk >> 5, c = blk & (NC_ - 1);
  const int t0 = c * CL_;
  const float* g = rec + ((size_t)bs * T_ + t0) * 128;
  for (int i = threadIdx.x; i < CL_ * 32; i += 256)
    *(float4*)(R + (size_t)i * 4) = *(const float4*)(g + (size_t)i * 4);
  __syncthreads();

  const int w = threadIdx.x >> 6, l = threadIdx.x & 63;
  const int v = w * 8 + (l & 7);
  const int n0 = (l >> 3) * 4;
  float s0 = 0.f, s1 = 0.f, s2 = 0.f, s3 = 0.f;
  float cum = 1.f;
  float* yl = ylocal + ((size_t)bs * T_ + t0) * 32 + v;
  float* cd = cumd + (size_t)bs * T_ + t0;

#pragma unroll 4
  for (int t = 0; t < CL_; ++t) {
    const float* r = R + t * 128;
    const float4 k4 = *(const float4*)(r + n0);
    const float4 q4 = *(const float4*)(r + 32 + n0);
    const float vv = r[64 + v];
    const float d  = r[96];
    cum *= d;
    s0 = fmaf(d, s0, k4.x * vv);
    s1 = fmaf(d, s1, k4.y * vv);
    s2 = fmaf(d, s2, k4.z * vv);
    s3 = fmaf(d, s3, k4.w * vv);
    float p = fmaf(q4.x, s0, fmaf(q4.y, s1, fmaf(q4.z, s2, q4.w * s3)));
    p += __shfl_xor(p, 8); p += __shfl_xor(p, 16); p += __shfl_xor(p, 32);
    if (l < 8) yl[(size_t)t * 32] = p;
    if (threadIdx.x == 0) cd[t] = cum;
  }
  float* sl = Sloc + (((size_t)bs * NC_ + c) * 32 + n0) * 32 + v;
  sl[0] = s0; sl[32] = s1; sl[64] = s2; sl[96] = s3;
  if (threadIdx.x == 0) Pc[bs * NC_ + c] = cum;
}

// ---------------------------------------------------------------- chunked scan: pass 2
__global__ __launch_bounds__(256) void scan_pass2(const float* __restrict__ Sloc,
                                                  const float* __restrict__ Pc,
                                                  const float* __restrict__ S0,
                                                  float* __restrict__ Sin,
                                                  float* __restrict__ Sfin) {
  __shared__ float Ps[NC_];
  const int bs = blockIdx.x;
  if (threadIdx.x < NC_) Ps[threadIdx.x] = Pc[bs * NC_ + threadIdx.x];
  __syncthreads();

  const int e0 = threadIdx.x * 4;
  const float* gl = Sloc + (size_t)bs * NC_ * 1024 + e0;
  float4 S = *(const float4*)(S0 + (size_t)bs * 1024 + e0);
  float* sin_b = Sin + (size_t)bs * NC_ * 1024 + e0;
#pragma unroll 8
  for (int c = 0; c < NC_; ++c) {
    const float4 sl = *(const float4*)(gl + (size_t)c * 1024);
    *(float4*)(sin_b + (size_t)c * 1024) = S;
    const float pc = Ps[c];
    S.x = fmaf(pc, S.x, sl.x);
    S.y = fmaf(pc, S.y, sl.y);
    S.z = fmaf(pc, S.z, sl.z);
    S.w = fmaf(pc, S.w, sl.w);
  }
  *(float4*)(Sfin + (size_t)bs * 1024 + e0) = S;
}

// ---------------------------------------------------------------- chunked scan: pass 3
__global__ __launch_bounds__(256) void scan_pass3(const float* __restrict__ rec,
                                                  const float* __restrict__ ylocal,
                                                  const float* __restrict__ Sin,
                                                  const float* __restrict__ cumd,
                                                  __hip_bfloat16* __restrict__ Y) {
  __shared__ __align__(16) float Ss[1024];
  const int blk = blockIdx.x;
  const int bs = blk >> 5, c = blk & (NC_ - 1);
  const int b = bs >> 3, s = bs & 7;
  const int t0 = c * CL_;
  {
    const float* gs = Sin + ((size_t)bs * NC_ + c) * 1024;
    const int i = threadIdx.x;
    *(float4*)(Ss + (size_t)i * 4) = *(const float4*)(gs + (size_t)i * 4);
  }
  __syncthreads();

  const int w = threadIdx.x >> 6, l = threadIdx.x & 63;
  const int v = l & 31;
#pragma unroll
  for (int i = 0; i < 16; i += 2) {
    const int t = t0 + w * 16 + i + (l >> 5);
    const float* r = rec + ((size_t)bs * T_ + t) * 128;
    float p = 0.f;
#pragma unroll
    for (int nq = 0; nq < 8; ++nq) {
      const float4 q4 = *(const float4*)(r + 32 + nq * 4);
      p = fmaf(q4.x, Ss[(nq * 4 + 0) * 32 + v], p);
      p = fmaf(q4.y, Ss[(nq * 4 + 1) * 32 + v], p);
      p = fmaf(q4.z, Ss[(nq * 4 + 2) * 32 + v], p);
      p = fmaf(q4.w, Ss[(nq * 4 + 3) * 32 + v], p);
    }
    const float wt   = r[97];
    const float cdv  = cumd[(size_t)bs * T_ + t];
    const float yloc = ylocal[((size_t)bs * T_ + t) * 32 + v];
    const long m = (long)b * T_ + t;
    Y[(size_t)m * 256 + s * 32 + v] = __float2bfloat16(wt * (yloc + cdv * p));
  }
}

// ---------------------------------------------------------------- launch
extern "C" void kernel_launch(void* const* d_in, const int* in_sizes, int n_in,
                              void* d_out, int out_size, void* d_ws, size_t ws_size,
                              hipStream_t stream) {
  const float* x       = (const float*)d_in[0];
  const float* Wr      = (const float*)d_in[1];
  const float* Wq      = (const float*)d_in[2];
  const float* Wk      = (const float*)d_in[3];
  const float* Wv      = (const float*)d_in[4];
  const float* Wa      = (const float*)d_in[5];
  const float* A_log   = (const float*)d_in[6];
  const float* dt_bias = (const float*)d_in[7];
  const float* Wo      = (const float*)d_in[8];
  const float* S0      = (const float*)d_in[9];
  float* out = (float*)d_out;

  char* p = (char*)d_ws;
  auto alloc = [&](size_t bytes) -> void* {
    void* r = (void*)p; p += (bytes + 255) & ~(size_t)255; return r;
  };
  __hip_bfloat16* x_bf = (__hip_bfloat16*)alloc((size_t)NTOK * DIM_ * 2);
  __hip_bfloat16* Wg   = (__hip_bfloat16*)alloc((size_t)H_ * 96 * DIM_ * 2);
  float* WTp  = (float*)alloc((size_t)DIM_ * RA_N * 4);
  float* RA   = (float*)alloc((size_t)NTOK * RA_N * 4);
  int*   idxb = (int*)  alloc((size_t)NPAIR * 4);
  float* rwb  = (float*)alloc((size_t)NPAIR * 4);
  float* decb = (float*)alloc((size_t)NPAIR * 4);
  int*   cnt  = (int*)  alloc(256);
  int*   pairtok = (int*)alloc((size_t)H_ * NTOK * 4);
  float* recb = (float*)alloc((size_t)NSLOT * T_ * 128 * 4);
  __hip_bfloat16* Yb = (__hip_bfloat16*)alloc((size_t)NTOK * 256 * 2);
  __hip_bfloat16* B2 = (__hip_bfloat16*)alloc((size_t)DIM_ * 256 * 2);
  float* ylocal = (float*)alloc((size_t)NSLOT * T_ * 32 * 4);
  float* Slocb  = (float*)alloc((size_t)NSLOT * NC_ * 1024 * 4);
  float* Pcb    = (float*)alloc((size_t)NSLOT * NC_ * 4);
  float* Sinb   = (float*)alloc((size_t)NSLOT * NC_ * 1024 * 4);
  float* cumdb  = (float*)alloc((size_t)NSLOT * T_ * 4);

  cast_bf16<<<NTOK * DIM_ / 4 / 256, 256, 0, stream>>>(x, x_bf, NTOK * DIM_ / 4);
  build_wg<<<H_ * 96 * DIM_ / 4 / 256, 256, 0, stream>>>(Wq, Wk, Wv, Wg);
  build_b2<<<DIM_ * 256 / 256, 256, 0, stream>>>(Wo, B2);
  build_wt<<<DIM_ * RA_N / 256, 256, 0, stream>>>(Wr, Wa, WTp);

  router_gemm<<<NTOK / 8, 256, 0, stream>>>(x, WTp, RA);
  router_topk<<<NTOK / 4, 256, 0, stream>>>(RA, A_log, dt_bias, idxb, rwb, decb);

  zero_cnt<<<1, 64, 0, stream>>>(cnt);
  hist_bucket<<<32, 256, 0, stream>>>(idxb, cnt, pairtok);

  grouped_qkv<<<8192, 256, 0, stream>>>(
      (const short*)x_bf, (const short*)Wg, pairtok, cnt, rwb, decb, recb);

  scan_pass1<<<NSLOT * NC_, 256, 0, stream>>>(recb, ylocal, Slocb, Pcb, cumdb);
  scan_pass2<<<NSLOT, 256, 0, stream>>>(Slocb, Pcb, S0, Sinb, out + (size_t)NTOK * DIM_);
  scan_pass3<<<NSLOT * NC_, 256, 0, stream>>>(recb, ylocal, Sinb, cumdb, Yb);

  gemm_bt<false><<<dim3(DIM_ / 128, NTOK / 128), 256, 0, stream>>>(
      (const short*)Yb, (const short*)B2, out, NTOK, DIM_, 256);
}

// Round 20
// 173.859 us; speedup vs baseline: 1.0750x; 1.0750x over previous
//
#include <hip/hip_runtime.h>
#include <hip/hip_bf16.h>

typedef __attribute__((ext_vector_type(8))) short bf16x8;
typedef __attribute__((ext_vector_type(4))) float f32x4;

#define B_   4
#define T_   2048
#define DIM_ 1024
#define H_   64
#define NS_  32
#define K_   8
#define HV_  32
#define NTOK  (B_ * T_)   /* 8192 */
#define RA_N  128         /* router logits(64) | a(64) */
#define CL_   64          /* scan chunk length */
#define NC_   (T_ / CL_)  /* 32 chunks per slot */
#define NSLOT (B_ * K_)   /* 32 */
#define NPAIR (NTOK * K_) /* 65536 */

// ---------------------------------------------------------------- helpers
__device__ __forceinline__ void gld_lds16(const void* g, void* s) {
  __builtin_amdgcn_global_load_lds(
      (const __attribute__((address_space(1))) void*)g,
      (__attribute__((address_space(3))) void*)s, 16, 0, 0);
}
__device__ __forceinline__ float silu_f(float x) { return x / (1.f + expf(-x)); }

// ---------------------------------------------------------------- prep
__global__ __launch_bounds__(256) void cast_bf16(const float* __restrict__ in,
                                                 __hip_bfloat16* __restrict__ out, int n4) {
  int i = blockIdx.x * 256 + threadIdx.x;
  if (i >= n4) return;
  const float4 v = *(const float4*)(in + (size_t)i * 4);
  union { short4 s4; __hip_bfloat16 h[4]; } u;
  u.h[0] = __float2bfloat16(v.x); u.h[1] = __float2bfloat16(v.y);
  u.h[2] = __float2bfloat16(v.z); u.h[3] = __float2bfloat16(v.w);
  *(short4*)(out + (size_t)i * 4) = u.s4;
}

// Wg[h][r][d], r<32: Wq[h*32+r], r<64: Wk[h*32+r-32], else Wv[h*32+r-64]  (bf16)
__global__ __launch_bounds__(256) void build_wg(const float* __restrict__ Wq,
                                                const float* __restrict__ Wk,
                                                const float* __restrict__ Wv,
                                                __hip_bfloat16* __restrict__ Wg) {
  int i = blockIdx.x * 256 + threadIdx.x;           // 6144*1024/4
  int row = i >> 8, c4 = (i & 255) * 4;
  int h = row / 96, r = row - h * 96;
  const float* src = (r < 32) ? (Wq + ((size_t)h * 32 + r) * 1024)
                   : (r < 64) ? (Wk + ((size_t)h * 32 + r - 32) * 1024)
                              : (Wv + ((size_t)h * 32 + r - 64) * 1024);
  const float4 v = *(const float4*)(src + c4);
  union { short4 s4; __hip_bfloat16 hh[4]; } u;
  u.hh[0] = __float2bfloat16(v.x); u.hh[1] = __float2bfloat16(v.y);
  u.hh[2] = __float2bfloat16(v.z); u.hh[3] = __float2bfloat16(v.w);
  *(short4*)(Wg + (size_t)row * 1024 + c4) = u.s4;
}

// B2[d][s*32+v] = Wo[d][v]  (slot-replicated Wo, bf16), 1024x256
__global__ __launch_bounds__(256) void build_b2(const float* __restrict__ Wo,
                                                __hip_bfloat16* __restrict__ B2) {
  int i = blockIdx.x * 256 + threadIdx.x;
  int d = i >> 8, c = i & 255;
  B2[i] = __float2bfloat16(Wo[d * 32 + (c & 31)]);
}

// WTp[(d>>2)*512 + h*4 + (d&3)] = (h<64 ? Wr : Wa)[h][d]  fp32 packed.
__global__ __launch_bounds__(256) void build_wt(const float* __restrict__ Wr,
                                                const float* __restrict__ Wa,
                                                float* __restrict__ WTp) {
  int i = blockIdx.x * 256 + threadIdx.x;           // 131072
  int d = i >> 7, h = i & 127;
  const float v = (h < 64) ? Wr[h * 1024 + d] : Wa[(h - 64) * 1024 + d];
  WTp[(d >> 2) * 512 + h * 4 + (d & 3)] = v;
}

// ---------------------------------------------------------------- router GEMM (fp32 exact)
// v6: R15's proven structure (LDS-broadcast x, compiler-scheduled VMEM weight
// loads — R18/R19 manual staging both regressed) scaled to 16 tokens/block:
// halves block count -> halves weight L2 re-fetch (512->256MB), doubles the
// FMA:load ratio per step (256 VALU-cyc per 2 loads). fp32 order per token
// identical to R15. LDS 64KB -> 2 blk/CU.
__global__ __launch_bounds__(256, 2) void router_gemm(const float* __restrict__ x,
                                                      const float* __restrict__ WTp,
                                                      float* __restrict__ RA) {
  __shared__ __align__(16) float Lx[16 * 1024];       // 64 KB
  const int w = threadIdx.x >> 6, l = threadIdx.x & 63;
  const int t0 = blockIdx.x * 16;
#pragma unroll
  for (int j = 0; j < 16; ++j) {
    const int seg = w * 16 + j;
    gld_lds16(x + (size_t)t0 * DIM_ + seg * 256 + l * 4, Lx + seg * 256);
  }
  asm volatile("s_waitcnt vmcnt(0)" ::: "memory");
  __builtin_amdgcn_s_barrier();

  const int dbase = w * 256;
  float a0[16] = {}, a1[16] = {};
#pragma unroll 2
  for (int d = dbase; d < dbase + 256; d += 4) {
    const float4 w0 = *(const float4*)(WTp + (size_t)(d >> 2) * 512 + l * 4);
    const float4 w1 = *(const float4*)(WTp + (size_t)(d >> 2) * 512 + (64 + l) * 4);
#pragma unroll
    for (int i = 0; i < 16; ++i) {
      const float4 xv = *(const float4*)(Lx + i * 1024 + d);
      a0[i] = fmaf(xv.x, w0.x, a0[i]);
      a0[i] = fmaf(xv.y, w0.y, a0[i]);
      a0[i] = fmaf(xv.z, w0.z, a0[i]);
      a0[i] = fmaf(xv.w, w0.w, a0[i]);
      a1[i] = fmaf(xv.x, w1.x, a1[i]);
      a1[i] = fmaf(xv.y, w1.y, a1[i]);
      a1[i] = fmaf(xv.z, w1.z, a1[i]);
      a1[i] = fmaf(xv.w, w1.w, a1[i]);
    }
  }
  __syncthreads();                       // all x reads done -> alias partials
  float* Lp = Lx;                        // [4][16][128] floats = 32 KB
#pragma unroll
  for (int i = 0; i < 16; ++i) {
    Lp[(w * 16 + i) * 128 + l] = a0[i];
    Lp[(w * 16 + i) * 128 + 64 + l] = a1[i];
  }
  __syncthreads();
  for (int o = threadIdx.x; o < 2048; o += 256) {
    const int ti = o >> 7, cc = o & 127;
    RA[(size_t)(t0 + ti) * RA_N + cc] =
        (Lp[(0 * 16 + ti) * 128 + cc] + Lp[(1 * 16 + ti) * 128 + cc]) +
        (Lp[(2 * 16 + ti) * 128 + cc] + Lp[(3 * 16 + ti) * 128 + cc]);
  }
}

// ---------------------------------------------------------------- top-k + decay (1 wave / token)
__global__ __launch_bounds__(256) void router_topk(const float* __restrict__ RA,
                                                   const float* __restrict__ A_log,
                                                   const float* __restrict__ dt_bias,
                                                   int* __restrict__ idxb,
                                                   float* __restrict__ rwb,
                                                   float* __restrict__ decb) {
  const int w = threadIdx.x >> 6, l = threadIdx.x & 63;
  const int m = blockIdx.x * 4 + w;
  float zcur = RA[(size_t)m * RA_N + l];
  const int idx = l;
  float z0 = 0.f, myz = 0.f;
  int myh = 0;
#pragma unroll
  for (int i = 0; i < 8; ++i) {
    float v = zcur; int vi = idx;
#pragma unroll
    for (int off = 1; off < 64; off <<= 1) {
      float ov = __shfl_xor(v, off);
      int   oi = __shfl_xor(vi, off);
      if (ov > v || (ov == v && oi < vi)) { v = ov; vi = oi; }
    }
    if (i == 0) z0 = v;
    if (l == i) { myz = v; myh = vi; }
    if (idx == vi) zcur = -__builtin_inff();
  }
  float e = (l < 8) ? expf(myz - z0) : 0.f;
  float es = e;
  es += __shfl_xor(es, 1); es += __shfl_xor(es, 2); es += __shfl_xor(es, 4);
  if (l < 8) {
    const float a  = RA[(size_t)m * RA_N + 64 + myh];
    const float xb = a + dt_bias[myh];
    const float dt = (xb > 20.f) ? xb : log1pf(expf(xb));
    idxb[m * 8 + l] = myh;
    rwb [m * 8 + l] = e / es;
    decb[m * 8 + l] = expf(-expf(A_log[myh]) * dt);
  }
}

// ---------------------------------------------------------------- head bucketing
__global__ void zero_cnt(int* __restrict__ cnt) {
  if (threadIdx.x < H_) cnt[threadIdx.x] = 0;
}

__global__ __launch_bounds__(256) void hist_bucket(const int* __restrict__ idxb,
                                                   int* __restrict__ cnt,
                                                   int* __restrict__ pairtok) {
  __shared__ int lh[H_];
  __shared__ int lcur[H_];
  const int tid = threadIdx.x;
  if (tid < H_) lh[tid] = 0;
  __syncthreads();
  const int base = blockIdx.x * (NPAIR / 32);   // 2048 pairs/block
  int hs[8];
#pragma unroll
  for (int j = 0; j < 8; ++j) {
    hs[j] = idxb[base + j * 256 + tid];
    atomicAdd(&lh[hs[j]], 1);
  }
  __syncthreads();
  if (tid < H_) lcur[tid] = atomicAdd(&cnt[tid], lh[tid]);
  __syncthreads();
#pragma unroll
  for (int j = 0; j < 8; ++j) {
    const int pos = atomicAdd(&lcur[hs[j]], 1);
    pairtok[hs[j] * NTOK + pos] = base + j * 256 + tid;
  }
}

// ---------------------------------------------------------------- grouped QKV projection
// R17 verified: 4 blk/CU, register prs via __shfl, 128B segments (1 cache
// line = transaction floor), counted vmcnt(5), both-sides XOR swizzle.
__global__ __launch_bounds__(256, 4) void grouped_qkv(const short* __restrict__ x_bf,
                                                      const short* __restrict__ Wg,
                                                      const int* __restrict__ pairtok,
                                                      const int* __restrict__ cnt,
                                                      const float* __restrict__ rwb,
                                                      const float* __restrict__ decb,
                                                      float* __restrict__ rec) {
  const int bid = blockIdx.x;
  const int h = bid & 63;                             // h%8 == bid%8 (XCD affinity)
  const int c = bid >> 6;                             // 0..127 chunk of 64 rows
  const int n = cnt[h];
  if (c * 64 >= n) return;
  __shared__ __align__(16) short stg[2][10240];       // 40,960 B exactly

  const int w = threadIdx.x >> 6, l = threadIdx.x & 63;
  const int lr = l & 15, lk = l >> 4;

  const int ri = c * 64 + w * 16 + l;
  int pid = -1;
  if (l < 16 && ri < n) pid = pairtok[h * NTOK + ri];
  const long fallback = (long)(pairtok[h * NTOK] >> 3);

  const int lrow8 = l >> 3, lslot = l & 7;
  const int swz = (lslot ^ lrow8) << 3;               // shorts within 64-short row
  const int p0 = __shfl(pid, lrow8);
  const int p1 = __shfl(pid, 8 + lrow8);
  const short* sa0 = x_bf + ((p0 >= 0) ? (long)(p0 >> 3) : fallback) * DIM_ + swz;
  const short* sa1 = x_bf + ((p1 >= 0) ? (long)(p1 >> 3) : fallback) * DIM_ + swz;
  const short* sb  = Wg + ((size_t)h * 96 + w * 24 + lrow8) * DIM_ + swz;

  auto STAGE = [&](int s, int t) {                    // 5 loads/wave
    const int k0 = t * 64;
    short* bb = stg[s];
    gld_lds16(sa0 + k0, bb + (w * 16) * 64);
    gld_lds16(sa1 + k0, bb + (w * 16 + 8) * 64);
#pragma unroll
    for (int j = 0; j < 3; ++j)
      gld_lds16(sb + (size_t)(j * 8) * DIM_ + k0, bb + 4096 + (w * 24 + j * 8) * 64);
  };

  f32x4 acc[6] = {};
  STAGE(0, 0);
  int cur = 0;
  for (int t = 0; t < 16; ++t) {
    if (t < 15) {
      STAGE(cur ^ 1, t + 1);
      asm volatile("s_waitcnt vmcnt(5) lgkmcnt(0)" ::: "memory");
    } else {
      asm volatile("s_waitcnt vmcnt(0) lgkmcnt(0)" ::: "memory");
    }
    __builtin_amdgcn_s_barrier();
    __builtin_amdgcn_sched_barrier(0);
    const short* bb = stg[cur];
#pragma unroll
    for (int kk = 0; kk < 2; ++kk) {
      const int sl = ((kk * 4 + lk) ^ (lr & 7)) << 3;
      const bf16x8 a = *(const bf16x8*)(bb + (w * 16 + lr) * 64 + sl);
#pragma unroll
      for (int j = 0; j < 6; ++j) {
        const bf16x8 bj = *(const bf16x8*)(bb + 4096 + (j * 16 + lr) * 64 + sl);
        acc[j] = __builtin_amdgcn_mfma_f32_16x16x32_bf16(a, bj, acc[j], 0, 0, 0);
      }
    }
    asm volatile("s_waitcnt lgkmcnt(0)" ::: "memory"); // reads retired before reuse
    __builtin_amdgcn_sched_barrier(0);
    __builtin_amdgcn_s_barrier();
    cur ^= 1;
  }

  // epilogue: row(within wave) = lk*4 + r; acc cols j0,j1=q j2,j3=k j4,j5=v
#pragma unroll
  for (int r = 0; r < 4; ++r) {
    const int p = __shfl(pid, lk * 4 + r);
    float q0v = silu_f(acc[0][r]), q1v = silu_f(acc[1][r]);
    float k0v = silu_f(acc[2][r]), k1v = silu_f(acc[3][r]);
    float v0 = silu_f(acc[4][r]), v1 = silu_f(acc[5][r]);
    float ssq = q0v * q0v + q1v * q1v;
    float ssk = k0v * k0v + k1v * k1v;
    ssq += __shfl_xor(ssq, 1); ssq += __shfl_xor(ssq, 2);
    ssq += __shfl_xor(ssq, 4); ssq += __shfl_xor(ssq, 8);
    ssk += __shfl_xor(ssk, 1); ssk += __shfl_xor(ssk, 2);
    ssk += __shfl_xor(ssk, 4); ssk += __shfl_xor(ssk, 8);
    const float rq = rsqrtf(ssq + 1e-6f), rk = rsqrtf(ssk + 1e-6f);
    if (p >= 0) {
      const int m = p >> 3, s = p & 7;
      const int b = m >> 11, t = m & (T_ - 1);
      float* rb = rec + (((size_t)(b * 8 + s)) * T_ + t) * 128;
      rb[lr]      = k0v * rk;
      rb[16 + lr] = k1v * rk;
      rb[32 + lr] = q0v * rq;
      rb[48 + lr] = q1v * rq;
      rb[64 + lr] = v0;
      rb[80 + lr] = v1;
      if (lr == 0) { rb[96] = decb[p]; rb[97] = rwb[p]; }
    }
  }
}

// ---------------------------------------------------------------- bf16 MFMA GEMM, C = A * B^T (final proj)
template <bool OUT_BF16>
__global__ __launch_bounds__(256) void gemm_bt(const short* __restrict__ A,
                                               const short* __restrict__ Bm,
                                               void* __restrict__ Cout,
                                               int M, int N, int K) {
  __shared__ __align__(16) short As[2][128 * 32];
  __shared__ __align__(16) short Bs[2][128 * 32];
  const int tid = threadIdx.x;
  const int w = tid >> 6, l = tid & 63;
  const int m0 = blockIdx.y * 128, n0 = blockIdx.x * 128;
  const int wr = (w >> 1) * 64, wc = (w & 1) * 64;
  const int rsub = l >> 2, csub = (l & 3) * 8;
  const int lr = l & 15, lk = l >> 4;
  f32x4 acc[4][4] = {};

  auto STAGE = [&](int buf, int k0) {
#pragma unroll
    for (int j = 0; j < 2; ++j) {
      const int ra = w * 32 + j * 16;
      gld_lds16(A  + (size_t)(m0 + ra + rsub) * K + k0 + csub, As[buf] + ra * 32);
      gld_lds16(Bm + (size_t)(n0 + ra + rsub) * K + k0 + csub, Bs[buf] + ra * 32);
    }
  };

  STAGE(0, 0);
  __syncthreads();
  int cur = 0;
  for (int k0 = 0; k0 < K; k0 += 32) {
    if (k0 + 32 < K) STAGE(cur ^ 1, k0 + 32);
    bf16x8 af[4], bfr[4];
#pragma unroll
    for (int i = 0; i < 4; ++i) af[i]  = *(const bf16x8*)(As[cur] + (wr + i * 16 + lr) * 32 + lk * 8);
#pragma unroll
    for (int j = 0; j < 4; ++j) bfr[j] = *(const bf16x8*)(Bs[cur] + (wc + j * 16 + lr) * 32 + lk * 8);
#pragma unroll
    for (int i = 0; i < 4; ++i)
#pragma unroll
      for (int j = 0; j < 4; ++j)
        acc[i][j] = __builtin_amdgcn_mfma_f32_16x16x32_bf16(af[i], bfr[j], acc[i][j], 0, 0, 0);
    __syncthreads();
    cur ^= 1;
  }
#pragma unroll
  for (int i = 0; i < 4; ++i)
#pragma unroll
    for (int j = 0; j < 4; ++j) {
      const size_t row0 = (size_t)m0 + wr + i * 16 + lk * 4;
      const size_t col  = (size_t)n0 + wc + j * 16 + lr;
#pragma unroll
      for (int r = 0; r < 4; ++r) {
        if constexpr (OUT_BF16)
          ((__hip_bfloat16*)Cout)[(row0 + r) * N + col] = __float2bfloat16(acc[i][j][r]);
        else
          ((float*)Cout)[(row0 + r) * N + col] = acc[i][j][r];
      }
    }
}

// ---------------------------------------------------------------- chunked scan: pass 1
__global__ __launch_bounds__(256) void scan_pass1(const float* __restrict__ rec,
                                                  float* __restrict__ ylocal,
                                                  float* __restrict__ Sloc,
                                                  float* __restrict__ Pc,
                                                  float* __restrict__ cumd) {
  __shared__ __align__(16) float R[CL_ * 128];   // 32 KB
  const int blk = blockIdx.x;
  const int bs = blk >> 5, c = blk & (NC_ - 1);
  const int t0 = c * CL_;
  const float* g = rec + ((size_t)bs * T_ + t0) * 128;
  for (int i = threadIdx.x; i < CL_ * 32; i += 256)
    *(float4*)(R + (size_t)i * 4) = *(const float4*)(g + (size_t)i * 4);
  __syncthreads();

  const int w = threadIdx.x >> 6, l = threadIdx.x & 63;
  const int v = w * 8 + (l & 7);
  const int n0 = (l >> 3) * 4;
  float s0 = 0.f, s1 = 0.f, s2 = 0.f, s3 = 0.f;
  float cum = 1.f;
  float* yl = ylocal + ((size_t)bs * T_ + t0) * 32 + v;
  float* cd = cumd + (size_t)bs * T_ + t0;

#pragma unroll 4
  for (int t = 0; t < CL_; ++t) {
    const float* r = R + t * 128;
    const float4 k4 = *(const float4*)(r + n0);
    const float4 q4 = *(const float4*)(r + 32 + n0);
    const float vv = r[64 + v];
    const float d  = r[96];
    cum *= d;
    s0 = fmaf(d, s0, k4.x * vv);
    s1 = fmaf(d, s1, k4.y * vv);
    s2 = fmaf(d, s2, k4.z * vv);
    s3 = fmaf(d, s3, k4.w * vv);
    float p = fmaf(q4.x, s0, fmaf(q4.y, s1, fmaf(q4.z, s2, q4.w * s3)));
    p += __shfl_xor(p, 8); p += __shfl_xor(p, 16); p += __shfl_xor(p, 32);
    if (l < 8) yl[(size_t)t * 32] = p;
    if (threadIdx.x == 0) cd[t] = cum;
  }
  float* sl = Sloc + (((size_t)bs * NC_ + c) * 32 + n0) * 32 + v;
  sl[0] = s0; sl[32] = s1; sl[64] = s2; sl[96] = s3;
  if (threadIdx.x == 0) Pc[bs * NC_ + c] = cum;
}

// ---------------------------------------------------------------- chunked scan: pass 2
__global__ __launch_bounds__(256) void scan_pass2(const float* __restrict__ Sloc,
                                                  const float* __restrict__ Pc,
                                                  const float* __restrict__ S0,
                                                  float* __restrict__ Sin,
                                                  float* __restrict__ Sfin) {
  __shared__ float Ps[NC_];
  const int bs = blockIdx.x;
  if (threadIdx.x < NC_) Ps[threadIdx.x] = Pc[bs * NC_ + threadIdx.x];
  __syncthreads();

  const int e0 = threadIdx.x * 4;
  const float* gl = Sloc + (size_t)bs * NC_ * 1024 + e0;
  float4 S = *(const float4*)(S0 + (size_t)bs * 1024 + e0);
  float* sin_b = Sin + (size_t)bs * NC_ * 1024 + e0;
#pragma unroll 8
  for (int c = 0; c < NC_; ++c) {
    const float4 sl = *(const float4*)(gl + (size_t)c * 1024);
    *(float4*)(sin_b + (size_t)c * 1024) = S;
    const float pc = Ps[c];
    S.x = fmaf(pc, S.x, sl.x);
    S.y = fmaf(pc, S.y, sl.y);
    S.z = fmaf(pc, S.z, sl.z);
    S.w = fmaf(pc, S.w, sl.w);
  }
  *(float4*)(Sfin + (size_t)bs * 1024 + e0) = S;
}

// ---------------------------------------------------------------- chunked scan: pass 3
__global__ __launch_bounds__(256) void scan_pass3(const float* __restrict__ rec,
                                                  const float* __restrict__ ylocal,
                                                  const float* __restrict__ Sin,
                                                  const float* __restrict__ cumd,
                                                  __hip_bfloat16* __restrict__ Y) {
  __shared__ __align__(16) float Ss[1024];
  const int blk = blockIdx.x;
  const int bs = blk >> 5, c = blk & (NC_ - 1);
  const int b = bs >> 3, s = bs & 7;
  const int t0 = c * CL_;
  {
    const float* gs = Sin + ((size_t)bs * NC_ + c) * 1024;
    const int i = threadIdx.x;
    *(float4*)(Ss + (size_t)i * 4) = *(const float4*)(gs + (size_t)i * 4);
  }
  __syncthreads();

  const int w = threadIdx.x >> 6, l = threadIdx.x & 63;
  const int v = l & 31;
#pragma unroll
  for (int i = 0; i < 16; i += 2) {
    const int t = t0 + w * 16 + i + (l >> 5);
    const float* r = rec + ((size_t)bs * T_ + t) * 128;
    float p = 0.f;
#pragma unroll
    for (int nq = 0; nq < 8; ++nq) {
      const float4 q4 = *(const float4*)(r + 32 + nq * 4);
      p = fmaf(q4.x, Ss[(nq * 4 + 0) * 32 + v], p);
      p = fmaf(q4.y, Ss[(nq * 4 + 1) * 32 + v], p);
      p = fmaf(q4.z, Ss[(nq * 4 + 2) * 32 + v], p);
      p = fmaf(q4.w, Ss[(nq * 4 + 3) * 32 + v], p);
    }
    const float wt   = r[97];
    const float cdv  = cumd[(size_t)bs * T_ + t];
    const float yloc = ylocal[((size_t)bs * T_ + t) * 32 + v];
    const long m = (long)b * T_ + t;
    Y[(size_t)m * 256 + s * 32 + v] = __float2bfloat16(wt * (yloc + cdv * p));
  }
}

// ---------------------------------------------------------------- launch
extern "C" void kernel_launch(void* const* d_in, const int* in_sizes, int n_in,
                              void* d_out, int out_size, void* d_ws, size_t ws_size,
                              hipStream_t stream) {
  const float* x       = (const float*)d_in[0];
  const float* Wr      = (const float*)d_in[1];
  const float* Wq      = (const float*)d_in[2];
  const float* Wk      = (const float*)d_in[3];
  const float* Wv      = (const float*)d_in[4];
  const float* Wa      = (const float*)d_in[5];
  const float* A_log   = (const float*)d_in[6];
  const float* dt_bias = (const float*)d_in[7];
  const float* Wo      = (const float*)d_in[8];
  const float* S0      = (const float*)d_in[9];
  float* out = (float*)d_out;

  char* p = (char*)d_ws;
  auto alloc = [&](size_t bytes) -> void* {
    void* r = (void*)p; p += (bytes + 255) & ~(size_t)255; return r;
  };
  __hip_bfloat16* x_bf = (__hip_bfloat16*)alloc((size_t)NTOK * DIM_ * 2);
  __hip_bfloat16* Wg   = (__hip_bfloat16*)alloc((size_t)H_ * 96 * DIM_ * 2);
  float* WTp  = (float*)alloc((size_t)DIM_ * RA_N * 4);
  float* RA   = (float*)alloc((size_t)NTOK * RA_N * 4);
  int*   idxb = (int*)  alloc((size_t)NPAIR * 4);
  float* rwb  = (float*)alloc((size_t)NPAIR * 4);
  float* decb = (float*)alloc((size_t)NPAIR * 4);
  int*   cnt  = (int*)  alloc(256);
  int*   pairtok = (int*)alloc((size_t)H_ * NTOK * 4);
  float* recb = (float*)alloc((size_t)NSLOT * T_ * 128 * 4);
  __hip_bfloat16* Yb = (__hip_bfloat16*)alloc((size_t)NTOK * 256 * 2);
  __hip_bfloat16* B2 = (__hip_bfloat16*)alloc((size_t)DIM_ * 256 * 2);
  float* ylocal = (float*)alloc((size_t)NSLOT * T_ * 32 * 4);
  float* Slocb  = (float*)alloc((size_t)NSLOT * NC_ * 1024 * 4);
  float* Pcb    = (float*)alloc((size_t)NSLOT * NC_ * 4);
  float* Sinb   = (float*)alloc((size_t)NSLOT * NC_ * 1024 * 4);
  float* cumdb  = (float*)alloc((size_t)NSLOT * T_ * 4);

  cast_bf16<<<NTOK * DIM_ / 4 / 256, 256, 0, stream>>>(x, x_bf, NTOK * DIM_ / 4);
  build_wg<<<H_ * 96 * DIM_ / 4 / 256, 256, 0, stream>>>(Wq, Wk, Wv, Wg);
  build_b2<<<DIM_ * 256 / 256, 256, 0, stream>>>(Wo, B2);
  build_wt<<<DIM_ * RA_N / 256, 256, 0, stream>>>(Wr, Wa, WTp);

  router_gemm<<<NTOK / 16, 256, 0, stream>>>(x, WTp, RA);
  router_topk<<<NTOK / 4, 256, 0, stream>>>(RA, A_log, dt_bias, idxb, rwb, decb);

  zero_cnt<<<1, 64, 0, stream>>>(cnt);
  hist_bucket<<<32, 256, 0, stream>>>(idxb, cnt, pairtok);

  grouped_qkv<<<8192, 256, 0, stream>>>(
      (const short*)x_bf, (const short*)Wg, pairtok, cnt, rwb, decb, recb);

  scan_pass1<<<NSLOT * NC_, 256, 0, stream>>>(recb, ylocal, Slocb, Pcb, cumdb);
  scan_pass2<<<NSLOT, 256, 0, stream>>>(Slocb, Pcb, S0, Sinb, out + (size_t)NTOK * DIM_);
  scan_pass3<<<NSLOT * NC_, 256, 0, stream>>>(recb, ylocal, Sinb, cumdb, Yb);

  gemm_bt<false><<<dim3(DIM_ / 128, NTOK / 128), 256, 0, stream>>>(
      (const short*)Yb, (const short*)B2, out, NTOK, DIM_, 256);
}

// Round 21
// 161.324 us; speedup vs baseline: 1.1585x; 1.0777x over previous
//
#include <hip/hip_runtime.h>
#include <hip/hip_bf16.h>

typedef __attribute__((ext_vector_type(8))) short bf16x8;
typedef __attribute__((ext_vector_type(4))) float f32x4;

#define B_   4
#define T_   2048
#define DIM_ 1024
#define H_   64
#define NS_  32
#define K_   8
#define HV_  32
#define NTOK  (B_ * T_)   /* 8192 */
#define RA_N  128         /* router logits(64) | a(64) */
#define CL_   64          /* scan chunk length */
#define NC_   (T_ / CL_)  /* 32 chunks per slot */
#define NSLOT (B_ * K_)   /* 32 */
#define NPAIR (NTOK * K_) /* 65536 */

// ---------------------------------------------------------------- helpers
__device__ __forceinline__ void gld_lds16(const void* g, void* s) {
  __builtin_amdgcn_global_load_lds(
      (const __attribute__((address_space(1))) void*)g,
      (__attribute__((address_space(3))) void*)s, 16, 0, 0);
}
__device__ __forceinline__ float silu_f(float x) { return x / (1.f + expf(-x)); }

// ---------------------------------------------------------------- prep
// Wg[h][r][d], r<32: Wq[h*32+r], r<64: Wk[h*32+r-32], else Wv[h*32+r-64]  (bf16)
__global__ __launch_bounds__(256) void build_wg(const float* __restrict__ Wq,
                                                const float* __restrict__ Wk,
                                                const float* __restrict__ Wv,
                                                __hip_bfloat16* __restrict__ Wg) {
  int i = blockIdx.x * 256 + threadIdx.x;           // 6144*1024/4
  int row = i >> 8, c4 = (i & 255) * 4;
  int h = row / 96, r = row - h * 96;
  const float* src = (r < 32) ? (Wq + ((size_t)h * 32 + r) * 1024)
                   : (r < 64) ? (Wk + ((size_t)h * 32 + r - 32) * 1024)
                              : (Wv + ((size_t)h * 32 + r - 64) * 1024);
  const float4 v = *(const float4*)(src + c4);
  union { short4 s4; __hip_bfloat16 hh[4]; } u;
  u.hh[0] = __float2bfloat16(v.x); u.hh[1] = __float2bfloat16(v.y);
  u.hh[2] = __float2bfloat16(v.z); u.hh[3] = __float2bfloat16(v.w);
  *(short4*)(Wg + (size_t)row * 1024 + c4) = u.s4;
}

// merged: B2[d][s*32+v] = Wo[d][v] (bf16, 1024x256)  and
// WTp[(d>>2)*512 + h*4 + (d&3)] = (h<64 ? Wr : Wa)[h][d] (fp32 packed)
__global__ __launch_bounds__(256) void build_misc(const float* __restrict__ Wo,
                                                  const float* __restrict__ Wr,
                                                  const float* __restrict__ Wa,
                                                  __hip_bfloat16* __restrict__ B2,
                                                  float* __restrict__ WTp) {
  int i = blockIdx.x * 256 + threadIdx.x;           // grid 1024*256 = 262144
  {
    int d = i >> 8, c = i & 255;
    B2[i] = __float2bfloat16(Wo[d * 32 + (c & 31)]);
  }
  if (i < 131072) {
    int d = i >> 7, h = i & 127;
    const float v = (h < 64) ? Wr[h * 1024 + d] : Wa[(h - 64) * 1024 + d];
    WTp[(d >> 2) * 512 + h * 4 + (d & 3)] = v;
  }
}

// ---------------------------------------------------------------- router GEMM (fp32 exact, R15 structure)
// + fused x->bf16 writeout from the staged LDS tile (replaces cast_bf16).
__global__ __launch_bounds__(256, 4) void router_gemm(const float* __restrict__ x,
                                                      const float* __restrict__ WTp,
                                                      float* __restrict__ RA,
                                                      __hip_bfloat16* __restrict__ x_bf) {
  __shared__ __align__(16) float Lx[8 * 1024];        // 32 KB
  const int w = threadIdx.x >> 6, l = threadIdx.x & 63;
  const int t0 = blockIdx.x * 8;
#pragma unroll
  for (int j = 0; j < 8; ++j) {
    const int seg = w * 8 + j;
    gld_lds16(x + (size_t)t0 * DIM_ + seg * 256 + l * 4, Lx + seg * 256);
  }
  asm volatile("s_waitcnt vmcnt(0)" ::: "memory");
  __builtin_amdgcn_s_barrier();

  const int dbase = w * 256;
  float a0[8] = {}, a1[8] = {};
#pragma unroll 2
  for (int d = dbase; d < dbase + 256; d += 4) {
    const float4 w0 = *(const float4*)(WTp + (size_t)(d >> 2) * 512 + l * 4);
    const float4 w1 = *(const float4*)(WTp + (size_t)(d >> 2) * 512 + (64 + l) * 4);
    float4 xv[8];
#pragma unroll
    for (int i = 0; i < 8; ++i) xv[i] = *(const float4*)(Lx + i * 1024 + d);
#pragma unroll
    for (int i = 0; i < 8; ++i) {
      a0[i] = fmaf(xv[i].x, w0.x, a0[i]);
      a0[i] = fmaf(xv[i].y, w0.y, a0[i]);
      a0[i] = fmaf(xv[i].z, w0.z, a0[i]);
      a0[i] = fmaf(xv[i].w, w0.w, a0[i]);
      a1[i] = fmaf(xv[i].x, w1.x, a1[i]);
      a1[i] = fmaf(xv[i].y, w1.y, a1[i]);
      a1[i] = fmaf(xv[i].z, w1.z, a1[i]);
      a1[i] = fmaf(xv[i].w, w1.w, a1[i]);
    }
  }

  // fused cast: Lx holds x[t0*1024 .. t0*1024+8192) linearly; emit bf16.
#pragma unroll
  for (int j = 0; j < 8; ++j) {
    const int i4 = (j * 256 + threadIdx.x) * 4;
    const float4 v = *(const float4*)(Lx + i4);
    union { short4 s4; __hip_bfloat16 hh[4]; } u;
    u.hh[0] = __float2bfloat16(v.x); u.hh[1] = __float2bfloat16(v.y);
    u.hh[2] = __float2bfloat16(v.z); u.hh[3] = __float2bfloat16(v.w);
    *(short4*)((short*)x_bf + (size_t)t0 * DIM_ + i4) = u.s4;
  }

  __syncthreads();                       // all Lx reads done -> alias partials
  float* Lp = Lx;                        // [4][8][128] floats
#pragma unroll
  for (int i = 0; i < 8; ++i) {
    Lp[w * 1024 + i * 128 + l] = a0[i];
    Lp[w * 1024 + i * 128 + 64 + l] = a1[i];
  }
  __syncthreads();
  for (int o = threadIdx.x; o < 1024; o += 256) {
    const int ti = o >> 7, cc = o & 127;
    RA[(size_t)(t0 + ti) * RA_N + cc] =
        (Lp[0 * 1024 + ti * 128 + cc] + Lp[1 * 1024 + ti * 128 + cc]) +
        (Lp[2 * 1024 + ti * 128 + cc] + Lp[3 * 1024 + ti * 128 + cc]);
  }
}

// ---------------------------------------------------------------- top-k + decay (1 wave / token)
// Block 0 also zeroes cnt (hist_bucket runs strictly after in stream order).
__global__ __launch_bounds__(256) void router_topk(const float* __restrict__ RA,
                                                   const float* __restrict__ A_log,
                                                   const float* __restrict__ dt_bias,
                                                   int* __restrict__ idxb,
                                                   float* __restrict__ rwb,
                                                   float* __restrict__ decb,
                                                   int* __restrict__ cnt) {
  if (blockIdx.x == 0 && threadIdx.x < H_) cnt[threadIdx.x] = 0;
  const int w = threadIdx.x >> 6, l = threadIdx.x & 63;
  const int m = blockIdx.x * 4 + w;
  float zcur = RA[(size_t)m * RA_N + l];
  const int idx = l;
  float z0 = 0.f, myz = 0.f;
  int myh = 0;
#pragma unroll
  for (int i = 0; i < 8; ++i) {
    float v = zcur; int vi = idx;
#pragma unroll
    for (int off = 1; off < 64; off <<= 1) {
      float ov = __shfl_xor(v, off);
      int   oi = __shfl_xor(vi, off);
      if (ov > v || (ov == v && oi < vi)) { v = ov; vi = oi; }
    }
    if (i == 0) z0 = v;
    if (l == i) { myz = v; myh = vi; }
    if (idx == vi) zcur = -__builtin_inff();
  }
  float e = (l < 8) ? expf(myz - z0) : 0.f;
  float es = e;
  es += __shfl_xor(es, 1); es += __shfl_xor(es, 2); es += __shfl_xor(es, 4);
  if (l < 8) {
    const float a  = RA[(size_t)m * RA_N + 64 + myh];
    const float xb = a + dt_bias[myh];
    const float dt = (xb > 20.f) ? xb : log1pf(expf(xb));
    idxb[m * 8 + l] = myh;
    rwb [m * 8 + l] = e / es;
    decb[m * 8 + l] = expf(-expf(A_log[myh]) * dt);
  }
}

// ---------------------------------------------------------------- head bucketing (R7 verified)
__global__ __launch_bounds__(256) void hist_bucket(const int* __restrict__ idxb,
                                                   int* __restrict__ cnt,
                                                   int* __restrict__ pairtok) {
  __shared__ int lh[H_];
  __shared__ int lcur[H_];
  const int tid = threadIdx.x;
  if (tid < H_) lh[tid] = 0;
  __syncthreads();
  const int base = blockIdx.x * (NPAIR / 32);   // 2048 pairs/block
  int hs[8];
#pragma unroll
  for (int j = 0; j < 8; ++j) {
    hs[j] = idxb[base + j * 256 + tid];
    atomicAdd(&lh[hs[j]], 1);
  }
  __syncthreads();
  if (tid < H_) lcur[tid] = atomicAdd(&cnt[tid], lh[tid]);
  __syncthreads();
#pragma unroll
  for (int j = 0; j < 8; ++j) {
    const int pos = atomicAdd(&lcur[hs[j]], 1);
    pairtok[hs[j] * NTOK + pos] = base + j * 256 + tid;
  }
}

// ---------------------------------------------------------------- grouped QKV projection (R17 verified)
// 4 blk/CU, register prs via __shfl, 128B segments (cache-line transaction
// floor), counted vmcnt(5), both-sides XOR swizzle, head-affine XCD map.
__global__ __launch_bounds__(256, 4) void grouped_qkv(const short* __restrict__ x_bf,
                                                      const short* __restrict__ Wg,
                                                      const int* __restrict__ pairtok,
                                                      const int* __restrict__ cnt,
                                                      const float* __restrict__ rwb,
                                                      const float* __restrict__ decb,
                                                      float* __restrict__ rec) {
  const int bid = blockIdx.x;
  const int h = bid & 63;                             // h%8 == bid%8 (XCD affinity)
  const int c = bid >> 6;                             // 0..127 chunk of 64 rows
  const int n = cnt[h];
  if (c * 64 >= n) return;
  __shared__ __align__(16) short stg[2][10240];       // 40,960 B exactly

  const int w = threadIdx.x >> 6, l = threadIdx.x & 63;
  const int lr = l & 15, lk = l >> 4;

  const int ri = c * 64 + w * 16 + l;
  int pid = -1;
  if (l < 16 && ri < n) pid = pairtok[h * NTOK + ri];
  const long fallback = (long)(pairtok[h * NTOK] >> 3);

  const int lrow8 = l >> 3, lslot = l & 7;
  const int swz = (lslot ^ lrow8) << 3;               // shorts within 64-short row
  const int p0 = __shfl(pid, lrow8);
  const int p1 = __shfl(pid, 8 + lrow8);
  const short* sa0 = x_bf + ((p0 >= 0) ? (long)(p0 >> 3) : fallback) * DIM_ + swz;
  const short* sa1 = x_bf + ((p1 >= 0) ? (long)(p1 >> 3) : fallback) * DIM_ + swz;
  const short* sb  = Wg + ((size_t)h * 96 + w * 24 + lrow8) * DIM_ + swz;

  auto STAGE = [&](int s, int t) {                    // 5 loads/wave
    const int k0 = t * 64;
    short* bb = stg[s];
    gld_lds16(sa0 + k0, bb + (w * 16) * 64);
    gld_lds16(sa1 + k0, bb + (w * 16 + 8) * 64);
#pragma unroll
    for (int j = 0; j < 3; ++j)
      gld_lds16(sb + (size_t)(j * 8) * DIM_ + k0, bb + 4096 + (w * 24 + j * 8) * 64);
  };

  f32x4 acc[6] = {};
  STAGE(0, 0);
  int cur = 0;
  for (int t = 0; t < 16; ++t) {
    if (t < 15) {
      STAGE(cur ^ 1, t + 1);
      asm volatile("s_waitcnt vmcnt(5) lgkmcnt(0)" ::: "memory");
    } else {
      asm volatile("s_waitcnt vmcnt(0) lgkmcnt(0)" ::: "memory");
    }
    __builtin_amdgcn_s_barrier();
    __builtin_amdgcn_sched_barrier(0);
    const short* bb = stg[cur];
#pragma unroll
    for (int kk = 0; kk < 2; ++kk) {
      const int sl = ((kk * 4 + lk) ^ (lr & 7)) << 3;
      const bf16x8 a = *(const bf16x8*)(bb + (w * 16 + lr) * 64 + sl);
#pragma unroll
      for (int j = 0; j < 6; ++j) {
        const bf16x8 bj = *(const bf16x8*)(bb + 4096 + (j * 16 + lr) * 64 + sl);
        acc[j] = __builtin_amdgcn_mfma_f32_16x16x32_bf16(a, bj, acc[j], 0, 0, 0);
      }
    }
    asm volatile("s_waitcnt lgkmcnt(0)" ::: "memory"); // reads retired before reuse
    __builtin_amdgcn_sched_barrier(0);
    __builtin_amdgcn_s_barrier();
    cur ^= 1;
  }

  // epilogue: row(within wave) = lk*4 + r; acc cols j0,j1=q j2,j3=k j4,j5=v
#pragma unroll
  for (int r = 0; r < 4; ++r) {
    const int p = __shfl(pid, lk * 4 + r);
    float q0v = silu_f(acc[0][r]), q1v = silu_f(acc[1][r]);
    float k0v = silu_f(acc[2][r]), k1v = silu_f(acc[3][r]);
    float v0 = silu_f(acc[4][r]), v1 = silu_f(acc[5][r]);
    float ssq = q0v * q0v + q1v * q1v;
    float ssk = k0v * k0v + k1v * k1v;
    ssq += __shfl_xor(ssq, 1); ssq += __shfl_xor(ssq, 2);
    ssq += __shfl_xor(ssq, 4); ssq += __shfl_xor(ssq, 8);
    ssk += __shfl_xor(ssk, 1); ssk += __shfl_xor(ssk, 2);
    ssk += __shfl_xor(ssk, 4); ssk += __shfl_xor(ssk, 8);
    const float rq = rsqrtf(ssq + 1e-6f), rk = rsqrtf(ssk + 1e-6f);
    if (p >= 0) {
      const int m = p >> 3, s = p & 7;
      const int b = m >> 11, t = m & (T_ - 1);
      float* rb = rec + (((size_t)(b * 8 + s)) * T_ + t) * 128;
      rb[lr]      = k0v * rk;
      rb[16 + lr] = k1v * rk;
      rb[32 + lr] = q0v * rq;
      rb[48 + lr] = q1v * rq;
      rb[64 + lr] = v0;
      rb[80 + lr] = v1;
      if (lr == 0) { rb[96] = decb[p]; rb[97] = rwb[p]; }
    }
  }
}

// ---------------------------------------------------------------- bf16 MFMA GEMM, C = A * B^T (final proj)
template <bool OUT_BF16>
__global__ __launch_bounds__(256) void gemm_bt(const short* __restrict__ A,
                                               const short* __restrict__ Bm,
                                               void* __restrict__ Cout,
                                               int M, int N, int K) {
  __shared__ __align__(16) short As[2][128 * 32];
  __shared__ __align__(16) short Bs[2][128 * 32];
  const int tid = threadIdx.x;
  const int w = tid >> 6, l = tid & 63;
  const int m0 = blockIdx.y * 128, n0 = blockIdx.x * 128;
  const int wr = (w >> 1) * 64, wc = (w & 1) * 64;
  const int rsub = l >> 2, csub = (l & 3) * 8;
  const int lr = l & 15, lk = l >> 4;
  f32x4 acc[4][4] = {};

  auto STAGE = [&](int buf, int k0) {
#pragma unroll
    for (int j = 0; j < 2; ++j) {
      const int ra = w * 32 + j * 16;
      gld_lds16(A  + (size_t)(m0 + ra + rsub) * K + k0 + csub, As[buf] + ra * 32);
      gld_lds16(Bm + (size_t)(n0 + ra + rsub) * K + k0 + csub, Bs[buf] + ra * 32);
    }
  };

  STAGE(0, 0);
  __syncthreads();
  int cur = 0;
  for (int k0 = 0; k0 < K; k0 += 32) {
    if (k0 + 32 < K) STAGE(cur ^ 1, k0 + 32);
    bf16x8 af[4], bfr[4];
#pragma unroll
    for (int i = 0; i < 4; ++i) af[i]  = *(const bf16x8*)(As[cur] + (wr + i * 16 + lr) * 32 + lk * 8);
#pragma unroll
    for (int j = 0; j < 4; ++j) bfr[j] = *(const bf16x8*)(Bs[cur] + (wc + j * 16 + lr) * 32 + lk * 8);
#pragma unroll
    for (int i = 0; i < 4; ++i)
#pragma unroll
      for (int j = 0; j < 4; ++j)
        acc[i][j] = __builtin_amdgcn_mfma_f32_16x16x32_bf16(af[i], bfr[j], acc[i][j], 0, 0, 0);
    __syncthreads();
    cur ^= 1;
  }
#pragma unroll
  for (int i = 0; i < 4; ++i)
#pragma unroll
    for (int j = 0; j < 4; ++j) {
      const size_t row0 = (size_t)m0 + wr + i * 16 + lk * 4;
      const size_t col  = (size_t)n0 + wc + j * 16 + lr;
#pragma unroll
      for (int r = 0; r < 4; ++r) {
        if constexpr (OUT_BF16)
          ((__hip_bfloat16*)Cout)[(row0 + r) * N + col] = __float2bfloat16(acc[i][j][r]);
        else
          ((float*)Cout)[(row0 + r) * N + col] = acc[i][j][r];
      }
    }
}

// ---------------------------------------------------------------- chunked scan: pass 1
__global__ __launch_bounds__(256) void scan_pass1(const float* __restrict__ rec,
                                                  float* __restrict__ ylocal,
                                                  float* __restrict__ Sloc,
                                                  float* __restrict__ Pc,
                                                  float* __restrict__ cumd) {
  __shared__ __align__(16) float R[CL_ * 128];   // 32 KB
  const int blk = blockIdx.x;
  const int bs = blk >> 5, c = blk & (NC_ - 1);
  const int t0 = c * CL_;
  const float* g = rec + ((size_t)bs * T_ + t0) * 128;
  for (int i = threadIdx.x; i < CL_ * 32; i += 256)
    *(float4*)(R + (size_t)i * 4) = *(const float4*)(g + (size_t)i * 4);
  __syncthreads();

  const int w = threadIdx.x >> 6, l = threadIdx.x & 63;
  const int v = w * 8 + (l & 7);
  const int n0 = (l >> 3) * 4;
  float s0 = 0.f, s1 = 0.f, s2 = 0.f, s3 = 0.f;
  float cum = 1.f;
  float* yl = ylocal + ((size_t)bs * T_ + t0) * 32 + v;
  float* cd = cumd + (size_t)bs * T_ + t0;

#pragma unroll 4
  for (int t = 0; t < CL_; ++t) {
    const float* r = R + t * 128;
    const float4 k4 = *(const float4*)(r + n0);
    const float4 q4 = *(const float4*)(r + 32 + n0);
    const float vv = r[64 + v];
    const float d  = r[96];
    cum *= d;
    s0 = fmaf(d, s0, k4.x * vv);
    s1 = fmaf(d, s1, k4.y * vv);
    s2 = fmaf(d, s2, k4.z * vv);
    s3 = fmaf(d, s3, k4.w * vv);
    float p = fmaf(q4.x, s0, fmaf(q4.y, s1, fmaf(q4.z, s2, q4.w * s3)));
    p += __shfl_xor(p, 8); p += __shfl_xor(p, 16); p += __shfl_xor(p, 32);
    if (l < 8) yl[(size_t)t * 32] = p;
    if (threadIdx.x == 0) cd[t] = cum;
  }
  float* sl = Sloc + (((size_t)bs * NC_ + c) * 32 + n0) * 32 + v;
  sl[0] = s0; sl[32] = s1; sl[64] = s2; sl[96] = s3;
  if (threadIdx.x == 0) Pc[bs * NC_ + c] = cum;
}

// ---------------------------------------------------------------- chunked scan: pass 2
__global__ __launch_bounds__(256) void scan_pass2(const float* __restrict__ Sloc,
                                                  const float* __restrict__ Pc,
                                                  const float* __restrict__ S0,
                                                  float* __restrict__ Sin,
                                                  float* __restrict__ Sfin) {
  __shared__ float Ps[NC_];
  const int bs = blockIdx.x;
  if (threadIdx.x < NC_) Ps[threadIdx.x] = Pc[bs * NC_ + threadIdx.x];
  __syncthreads();

  const int e0 = threadIdx.x * 4;
  const float* gl = Sloc + (size_t)bs * NC_ * 1024 + e0;
  float4 S = *(const float4*)(S0 + (size_t)bs * 1024 + e0);
  float* sin_b = Sin + (size_t)bs * NC_ * 1024 + e0;
#pragma unroll 8
  for (int c = 0; c < NC_; ++c) {
    const float4 sl = *(const float4*)(gl + (size_t)c * 1024);
    *(float4*)(sin_b + (size_t)c * 1024) = S;
    const float pc = Ps[c];
    S.x = fmaf(pc, S.x, sl.x);
    S.y = fmaf(pc, S.y, sl.y);
    S.z = fmaf(pc, S.z, sl.z);
    S.w = fmaf(pc, S.w, sl.w);
  }
  *(float4*)(Sfin + (size_t)bs * 1024 + e0) = S;
}

// ---------------------------------------------------------------- chunked scan: pass 3
__global__ __launch_bounds__(256) void scan_pass3(const float* __restrict__ rec,
                                                  const float* __restrict__ ylocal,
                                                  const float* __restrict__ Sin,
                                                  const float* __restrict__ cumd,
                                                  __hip_bfloat16* __restrict__ Y) {
  __shared__ __align__(16) float Ss[1024];
  const int blk = blockIdx.x;
  const int bs = blk >> 5, c = blk & (NC_ - 1);
  const int b = bs >> 3, s = bs & 7;
  const int t0 = c * CL_;
  {
    const float* gs = Sin + ((size_t)bs * NC_ + c) * 1024;
    const int i = threadIdx.x;
    *(float4*)(Ss + (size_t)i * 4) = *(const float4*)(gs + (size_t)i * 4);
  }
  __syncthreads();

  const int w = threadIdx.x >> 6, l = threadIdx.x & 63;
  const int v = l & 31;
#pragma unroll
  for (int i = 0; i < 16; i += 2) {
    const int t = t0 + w * 16 + i + (l >> 5);
    const float* r = rec + ((size_t)bs * T_ + t) * 128;
    float p = 0.f;
#pragma unroll
    for (int nq = 0; nq < 8; ++nq) {
      const float4 q4 = *(const float4*)(r + 32 + nq * 4);
      p = fmaf(q4.x, Ss[(nq * 4 + 0) * 32 + v], p);
      p = fmaf(q4.y, Ss[(nq * 4 + 1) * 32 + v], p);
      p = fmaf(q4.z, Ss[(nq * 4 + 2) * 32 + v], p);
      p = fmaf(q4.w, Ss[(nq * 4 + 3) * 32 + v], p);
    }
    const float wt   = r[97];
    const float cdv  = cumd[(size_t)bs * T_ + t];
    const float yloc = ylocal[((size_t)bs * T_ + t) * 32 + v];
    const long m = (long)b * T_ + t;
    Y[(size_t)m * 256 + s * 32 + v] = __float2bfloat16(wt * (yloc + cdv * p));
  }
}

// ---------------------------------------------------------------- launch
extern "C" void kernel_launch(void* const* d_in, const int* in_sizes, int n_in,
                              void* d_out, int out_size, void* d_ws, size_t ws_size,
                              hipStream_t stream) {
  const float* x       = (const float*)d_in[0];
  const float* Wr      = (const float*)d_in[1];
  const float* Wq      = (const float*)d_in[2];
  const float* Wk      = (const float*)d_in[3];
  const float* Wv      = (const float*)d_in[4];
  const float* Wa      = (const float*)d_in[5];
  const float* A_log   = (const float*)d_in[6];
  const float* dt_bias = (const float*)d_in[7];
  const float* Wo      = (const float*)d_in[8];
  const float* S0      = (const float*)d_in[9];
  float* out = (float*)d_out;

  char* p = (char*)d_ws;
  auto alloc = [&](size_t bytes) -> void* {
    void* r = (void*)p; p += (bytes + 255) & ~(size_t)255; return r;
  };
  __hip_bfloat16* x_bf = (__hip_bfloat16*)alloc((size_t)NTOK * DIM_ * 2);
  __hip_bfloat16* Wg   = (__hip_bfloat16*)alloc((size_t)H_ * 96 * DIM_ * 2);
  float* WTp  = (float*)alloc((size_t)DIM_ * RA_N * 4);
  float* RA   = (float*)alloc((size_t)NTOK * RA_N * 4);
  int*   idxb = (int*)  alloc((size_t)NPAIR * 4);
  float* rwb  = (float*)alloc((size_t)NPAIR * 4);
  float* decb = (float*)alloc((size_t)NPAIR * 4);
  int*   cnt  = (int*)  alloc(256);
  int*   pairtok = (int*)alloc((size_t)H_ * NTOK * 4);
  float* recb = (float*)alloc((size_t)NSLOT * T_ * 128 * 4);
  __hip_bfloat16* Yb = (__hip_bfloat16*)alloc((size_t)NTOK * 256 * 2);
  __hip_bfloat16* B2 = (__hip_bfloat16*)alloc((size_t)DIM_ * 256 * 2);
  float* ylocal = (float*)alloc((size_t)NSLOT * T_ * 32 * 4);
  float* Slocb  = (float*)alloc((size_t)NSLOT * NC_ * 1024 * 4);
  float* Pcb    = (float*)alloc((size_t)NSLOT * NC_ * 4);
  float* Sinb   = (float*)alloc((size_t)NSLOT * NC_ * 1024 * 4);
  float* cumdb  = (float*)alloc((size_t)NSLOT * T_ * 4);

  build_wg<<<H_ * 96 * DIM_ / 4 / 256, 256, 0, stream>>>(Wq, Wk, Wv, Wg);
  build_misc<<<DIM_ * 256 / 256, 256, 0, stream>>>(Wo, Wr, Wa, B2, WTp);

  router_gemm<<<NTOK / 8, 256, 0, stream>>>(x, WTp, RA, x_bf);
  router_topk<<<NTOK / 4, 256, 0, stream>>>(RA, A_log, dt_bias, idxb, rwb, decb, cnt);

  hist_bucket<<<32, 256, 0, stream>>>(idxb, cnt, pairtok);

  grouped_qkv<<<8192, 256, 0, stream>>>(
      (const short*)x_bf, (const short*)Wg, pairtok, cnt, rwb, decb, recb);

  scan_pass1<<<NSLOT * NC_, 256, 0, stream>>>(recb, ylocal, Slocb, Pcb, cumdb);
  scan_pass2<<<NSLOT, 256, 0, stream>>>(Slocb, Pcb, S0, Sinb, out + (size_t)NTOK * DIM_);
  scan_pass3<<<NSLOT * NC_, 256, 0, stream>>>(recb, ylocal, Sinb, cumdb, Yb);

  gemm_bt<false><<<dim3(DIM_ / 128, NTOK / 128), 256, 0, stream>>>(
      (const short*)Yb, (const short*)B2, out, NTOK, DIM_, 256);
}